// Round 6
// baseline (970.613 us; speedup 1.0000x reference)
//
#include <hip/hip_runtime.h>

#define B_ 8
#define M_ 4096
#define W_ 128
#define C_ 32
#define NN_ 16

static __device__ __forceinline__ float safeexp(float a) {
  return expf(fminf(a, 87.f));          // upper clamp only (ref has no overflow in-dist)
}

// ---------------------------------------------------------------- poison (diagnostic sentinel)
__global__ void poison_kernel(float* __restrict__ out, int n, float val) {
  int t = blockIdx.x * blockDim.x + threadIdx.x;
  if (t < n) out[t] = val;
}

// ---------------------------------------------------------------- init: fc1acc = fc1b; bn slots = 0
__global__ __launch_bounds__(256) void init_kernel(
    float* __restrict__ fc1acc, const float* __restrict__ fc1b,
    float* __restrict__ bn) {
  int g = blockIdx.x * 256 + threadIdx.x;
  if (g < 2048) fc1acc[g] = fc1b[g & 255];
  else if (g < 34816) bn[g - 2048] = 0.f;
}

// ---------------------------------------------------------------- attention: one THREAD per row
__global__ __launch_bounds__(256) void attn_kernel(
    const float* __restrict__ pseudo, const int* __restrict__ Lidx,
    const float* __restrict__ edge_w, const float* __restrict__ edge_b,
    const float* __restrict__ mu0, const float* __restrict__ sg0,
    const float* __restrict__ mu1, const float* __restrict__ sg1,
    float* __restrict__ we0, float* __restrict__ we1, int* __restrict__ colb) {
  int m = blockIdx.x * 256 + threadIdx.x;
  if (m >= M_) return;
  float w0[NN_], w1[NN_];
  int col[NN_];
#pragma unroll
  for (int n = 0; n < NN_; n++) {
    int e = m * NN_ + n;
    float p0 = pseudo[e * 2], p1 = pseudo[e * 2 + 1];
    float emb[5];
#pragma unroll
    for (int d = 0; d < 5; d++)
      emb[d] = p0 * edge_w[d * 2] + p1 * edge_w[d * 2 + 1] + edge_b[d];
    float a0 = 0.f, a1 = 0.f;
#pragma unroll
    for (int j = 0; j < 4; j++) {
      float qa = 0.f, qb = 0.f;
#pragma unroll
      for (int d = 0; d < 5; d++) {
        float u0 = emb[d] - mu0[j * 5 + d];
        qa += u0 * u0 * sg0[j * 5 + d];
        float u1 = emb[d] - mu1[j * 5 + d];
        qb += u1 * u1 * sg1[j * 5 + d];
      }
      a0 += safeexp(-0.5f * qa);
      a1 += safeexp(-0.5f * qb);
    }
    w0[n] = a0; w1[n] = a1;
    col[n] = Lidx[e] % M_;
  }
  float mx0 = w0[0], mx1 = w1[0];
#pragma unroll
  for (int n = 1; n < NN_; n++) { mx0 = fmaxf(mx0, w0[n]); mx1 = fmaxf(mx1, w1[n]); }
  float s0 = 0.f, s1 = 0.f;
#pragma unroll
  for (int n = 0; n < NN_; n++) {
    w0[n] = safeexp(w0[n] - mx0); s0 += w0[n];
    w1[n] = safeexp(w1[n] - mx1); s1 += w1[n];
  }
  float r0 = 1.f / s0, r1 = 1.f / s1;
#pragma unroll
  for (int n = 0; n < NN_; n++) {
    bool last = true;                       // numpy fancy-set: last duplicate wins
#pragma unroll
    for (int n2 = n + 1; n2 < NN_; n2++)
      if (col[n2] == col[n]) last = false;
    int e = m * NN_ + n;
    we0[e] = last ? w0[n] * r0 : 0.f;
    we1[e] = last ? w1[n] * r1 : 0.f;
    colb[e] = col[n];
  }
}

// ---------------------------------------------------------------- proj0: G1 = x@l1w0.T, G2 = x@l2w0.T
// (L@x)@W.T == L@(x@W.T): project first, gather second (32-wide instead of 128-wide)
__global__ __launch_bounds__(256) void proj0_kernel(
    const float* __restrict__ x, const float* __restrict__ l1w0,
    const float* __restrict__ l2w0, float* __restrict__ G1, float* __restrict__ G2) {
  int t = blockIdx.x * 256 + threadIdx.x;   // 1,048,576 = 32768 rows x 32 ch
  int r = t >> 5, c = t & 31;
  const float* xr  = x    + (size_t)r * 128;
  const float* w1r = l1w0 + c * 128;
  const float* w2r = l2w0 + c * 128;
  float a1 = 0.f, a2 = 0.f;
#pragma unroll 8
  for (int k = 0; k < 128; k++) {
    float xv = xr[k];
    a1 += xv * w1r[k];
    a2 += xv * w2r[k];
  }
  G1[t] = a1; G2[t] = a2;
}

// ---------------------------------------------------------------- conv0: h0 = L.G1 + G2 + b; BN0 partials
__global__ __launch_bounds__(256) void conv0_kernel(
    const float* __restrict__ G1, const float* __restrict__ G2,
    const float* __restrict__ we0, const int* __restrict__ colb,
    const float* __restrict__ l1b0, const float* __restrict__ l2b0,
    float* __restrict__ h0, float* __restrict__ bns, float* __restrict__ bnq) {
  int t = blockIdx.x * 256 + threadIdx.x;
  int r = t >> 5, c = t & 31;
  int b = r >> 12, m = r & 4095;
  const float* Gb = G1 + ((size_t)b << 17);   // b*4096*32
  float acc = 0.f;
  int eb = m << 4;
#pragma unroll 4
  for (int nn = 0; nn < NN_; nn++) {
    float wv = we0[eb + nn];
    int cn = colb[eb + nn];
    acc += wv * Gb[cn * 32 + c];
  }
  float hv = acc + G2[t] + l1b0[c] + l2b0[c];
  h0[t] = hv;
  int slot = blockIdx.x & 255;
  atomicAdd(&bns[c * 256 + slot], hv);
  atomicAdd(&bnq[c * 256 + slot], hv * hv);
}

// ---------------------------------------------------------------- BN finalize (sum 256 slots)
__global__ void bnfin_kernel(const float* __restrict__ bns, const float* __restrict__ bnq,
                             const float* __restrict__ g, const float* __restrict__ bb,
                             float* __restrict__ scale, float* __restrict__ shift) {
  int c = threadIdx.x;
  if (c >= 32) return;
  float s = 0.f, q = 0.f;
  for (int i = 0; i < 256; i++) { s += bns[c * 256 + i]; q += bnq[c * 256 + i]; }
  float mean = s * (1.f / 32768.f);
  float var = fmaxf(q * (1.f / 32768.f) - mean * mean, 0.f);
  float sc = g[c] * rsqrtf(var + 1e-5f);
  scale[c] = sc;
  shift[c] = bb[c] - mean * sc;
}

// ---------------------------------------------------------------- proj1: a=relu(bn0(h0)); G1=a@l1w1.T, G2=a@l2w1.T
__global__ __launch_bounds__(256) void proj1_kernel(
    const float* __restrict__ h0, const float* __restrict__ sc0,
    const float* __restrict__ l1w1, const float* __restrict__ l2w1,
    float* __restrict__ G1, float* __restrict__ G2) {
  int t = blockIdx.x * 256 + threadIdx.x;
  int r = t >> 5, c = t & 31;
  const float* hr = h0 + (size_t)r * 32;
  const float* w1r = l1w1 + c * 32;
  const float* w2r = l2w1 + c * 32;
  float a1 = 0.f, a2 = 0.f;
#pragma unroll
  for (int k = 0; k < 32; k++) {
    float av = fmaxf(hr[k] * sc0[k] + sc0[32 + k], 0.f);
    a1 += av * w1r[k];
    a2 += av * w2r[k];
  }
  G1[t] = a1; G2[t] = a2;
}

// ---------------------------------------------------------------- conv1: h1 = L.G1 + G2 + b; BN1 partials
__global__ __launch_bounds__(256) void conv1_kernel(
    const float* __restrict__ G1, const float* __restrict__ G2,
    const float* __restrict__ we1, const int* __restrict__ colb,
    const float* __restrict__ l1b1, const float* __restrict__ l2b1,
    float* __restrict__ h1, float* __restrict__ bns, float* __restrict__ bnq) {
  int t = blockIdx.x * 256 + threadIdx.x;
  int r = t >> 5, c = t & 31;
  int b = r >> 12, m = r & 4095;
  const float* Gb = G1 + ((size_t)b << 17);
  float acc = 0.f;
  int eb = m << 4;
#pragma unroll 4
  for (int nn = 0; nn < NN_; nn++) {
    float wv = we1[eb + nn];
    int cn = colb[eb + nn];
    acc += wv * Gb[cn * 32 + c];
  }
  float hv = acc + G2[t] + l1b1[c] + l2b1[c];
  h1[t] = hv;
  int slot = blockIdx.x & 255;
  atomicAdd(&bns[c * 256 + slot], hv);
  atomicAdd(&bnq[c * 256 + slot], hv * hv);
}

// ---------------------------------------------------------------- fc1: block=(b,kchunk); thread=o; atomic acc
__global__ __launch_bounds__(256) void fc1_kernel(
    const float* __restrict__ h1, const float* __restrict__ sc1,
    const float* __restrict__ fc1w, float* __restrict__ fc1acc) {
  __shared__ float a1s[1024];
  int kc = blockIdx.x >> 3;                 // 0..127
  int b  = blockIdx.x & 7;
  int kbase = kc << 10;
  for (int k = threadIdx.x; k < 1024; k += 256) {
    int kg = kbase + k;
    int c = kg & 31;
    a1s[k] = fmaxf(h1[((size_t)b << 17) + kg] * sc1[c] + sc1[32 + c], 0.f);
  }
  __syncthreads();
  int o = threadIdx.x;
  const float* wr = fc1w + (size_t)o * 131072 + kbase;
  float acc = 0.f;
#pragma unroll 8
  for (int k = 0; k < 1024; k++) acc += a1s[k] * wr[k];
  atomicAdd(&fc1acc[b * 256 + o], acc);
}

// ---------------------------------------------------------------- fc2 -> fp32 out
__global__ void fc2_kernel(const float* __restrict__ fc1acc,
                           const float* __restrict__ fc2w,
                           const float* __restrict__ fc2b,
                           float* __restrict__ out) {
  int t = blockIdx.x * blockDim.x + threadIdx.x;
  if (t >= 424) return;
  int b = t / 53, j = t - b * 53;
  float s = fc2b[j];
  const float* fa = fc1acc + b * 256;
  const float* wr = fc2w + j * 256;
#pragma unroll 8
  for (int o = 0; o < 256; o++) s += fmaxf(fa[o], 0.f) * wr[o];
  out[t] = s;
}

// ---------------------------------------------------------------- launch
extern "C" void kernel_launch(void* const* d_in, const int* in_sizes, int n_in,
                              void* d_out, int out_size, void* d_ws, size_t ws_size,
                              hipStream_t stream) {
  float* out = (float*)d_out;
  // ---- assumption sentinels: absmax ~= N*1e6 identifies the false assumption
  int bad = 0;
  if (n_in != 25) bad = 2;
  else if (in_sizes[0] != 4194304) bad = 3;       // x = B*M*W
  else if (in_sizes[1] != 131072) bad = 7;        // pseudo = M*NN*EMB
  else if (in_sizes[2] != 65536) bad = 4;         // L_idx = M*NN
  else if (in_sizes[9] != 4096) bad = 8;          // l1w0 = C*W
  else if (in_sizes[13] != 1024) bad = 9;         // l1w1 = C*C
  else if (in_sizes[21] != 33554432) bad = 5;     // fc1w = 256*M*C
  else if (out_size != 424) bad = 6;              // B*53
  else if (ws_size < 13509120) bad = 1;           // our workspace need
  if (bad) {
    poison_kernel<<<2, 256, 0, stream>>>(out, out_size, (float)bad * 1.0e6f);
    return;
  }

  const float* x      = (const float*)d_in[0];
  const float* pseudo = (const float*)d_in[1];
  const int*   Lidx   = (const int*)d_in[2];
  const float* edge_w = (const float*)d_in[3];
  const float* edge_b = (const float*)d_in[4];
  const float* mu0    = (const float*)d_in[5];
  const float* sg0    = (const float*)d_in[6];
  const float* mu1    = (const float*)d_in[7];
  const float* sg1    = (const float*)d_in[8];
  const float* l1w0   = (const float*)d_in[9];
  const float* l1b0   = (const float*)d_in[10];
  const float* l2w0   = (const float*)d_in[11];
  const float* l2b0   = (const float*)d_in[12];
  const float* l1w1   = (const float*)d_in[13];
  const float* l1b1   = (const float*)d_in[14];
  const float* l2w1   = (const float*)d_in[15];
  const float* l2b1   = (const float*)d_in[16];
  const float* bng0   = (const float*)d_in[17];
  const float* bnb0   = (const float*)d_in[18];
  const float* bng1   = (const float*)d_in[19];
  const float* bnb1   = (const float*)d_in[20];
  const float* fc1w   = (const float*)d_in[21];
  const float* fc1b   = (const float*)d_in[22];
  const float* fc2w   = (const float*)d_in[23];
  const float* fc2b   = (const float*)d_in[24];

  char* Wp = (char*)d_ws;
  int*   colb   = (int*)  (Wp + 0);          // 65536 i32
  float* we0    = (float*)(Wp + 262144);     // 65536 f32
  float* we1    = (float*)(Wp + 524288);     // 65536 f32
  float* G1     = (float*)(Wp + 786432);     // 32768x32 f32 (4 MB)
  float* G2     = (float*)(Wp + 4980736);    // 32768x32 f32 (4 MB)
  float* h0     = (float*)(Wp + 9175040);    // 32768x32 f32 (4 MB)
  float* h1     = (float*)(Wp + 9175040);    // aliases h0 (h0 dead after proj1)
  float* bn     = (float*)(Wp + 13369344);   // 4 x (32ch x 256 slots) f32
  float* sc     = (float*)(Wp + 13500416);   // scale0,shift0,scale1,shift1
  float* fc1acc = (float*)(Wp + 13500928);   // 8x256 f32

  init_kernel<<<136, 256, 0, stream>>>(fc1acc, fc1b, bn);
  attn_kernel<<<16, 256, 0, stream>>>(pseudo, Lidx, edge_w, edge_b,
                                      mu0, sg0, mu1, sg1, we0, we1, colb);
  proj0_kernel<<<4096, 256, 0, stream>>>(x, l1w0, l2w0, G1, G2);
  conv0_kernel<<<4096, 256, 0, stream>>>(G1, G2, we0, colb, l1b0, l2b0,
                                         h0, bn, bn + 8192);
  bnfin_kernel<<<1, 32, 0, stream>>>(bn, bn + 8192, bng0, bnb0, sc, sc + 32);
  proj1_kernel<<<4096, 256, 0, stream>>>(h0, sc, l1w1, l2w1, G1, G2);
  conv1_kernel<<<4096, 256, 0, stream>>>(G1, G2, we1, colb, l1b1, l2b1,
                                         h1, bn + 16384, bn + 24576);
  bnfin_kernel<<<1, 32, 0, stream>>>(bn + 16384, bn + 24576, bng1, bnb1,
                                     sc + 64, sc + 96);
  fc1_kernel<<<1024, 256, 0, stream>>>(h1, sc + 64, fc1w, fc1acc);
  fc2_kernel<<<2, 256, 0, stream>>>(fc1acc, fc2w, fc2b, out);
}

// Round 7
// 570.152 us; speedup vs baseline: 1.7024x; 1.7024x over previous
//
#include <hip/hip_runtime.h>

#define B_ 8
#define M_ 4096
#define W_ 128
#define C_ 32
#define NN_ 16

typedef short s16x8 __attribute__((ext_vector_type(8)));
typedef float f32x4 __attribute__((ext_vector_type(4)));

static __device__ __forceinline__ unsigned short f2bf(float f) {
  unsigned u = __builtin_bit_cast(unsigned, f);
  u = u + 0x7FFFu + ((u >> 16) & 1u);   // RNE
  return (unsigned short)(u >> 16);
}
static __device__ __forceinline__ s16x8 cvt8v(float4 a, float4 b) {
  s16x8 r;
  r[0] = (short)f2bf(a.x); r[1] = (short)f2bf(a.y);
  r[2] = (short)f2bf(a.z); r[3] = (short)f2bf(a.w);
  r[4] = (short)f2bf(b.x); r[5] = (short)f2bf(b.y);
  r[6] = (short)f2bf(b.z); r[7] = (short)f2bf(b.w);
  return r;
}
static __device__ __forceinline__ float safeexp(float a) {
  return expf(fminf(a, 87.f));
}

// ---------------------------------------------------------------- poison (diagnostic sentinel)
__global__ void poison_kernel(float* __restrict__ out, int n, float val) {
  int t = blockIdx.x * blockDim.x + threadIdx.x;
  if (t < n) out[t] = val;
}

// ---------------------------------------------------------------- init: fc1acc = fc1b; bn slots = 0
__global__ __launch_bounds__(256) void init_kernel(
    float* __restrict__ fc1acc, const float* __restrict__ fc1b,
    float* __restrict__ bn) {
  int g = blockIdx.x * 256 + threadIdx.x;
  if (g < 2048) fc1acc[g] = fc1b[g & 255];
  else if (g < 34816) bn[g - 2048] = 0.f;
}

// ---------------------------------------------------------------- attention: one THREAD per row (unchanged, passing)
__global__ __launch_bounds__(256) void attn_kernel(
    const float* __restrict__ pseudo, const int* __restrict__ Lidx,
    const float* __restrict__ edge_w, const float* __restrict__ edge_b,
    const float* __restrict__ mu0, const float* __restrict__ sg0,
    const float* __restrict__ mu1, const float* __restrict__ sg1,
    float* __restrict__ we0, float* __restrict__ we1, int* __restrict__ colb) {
  int m = blockIdx.x * 256 + threadIdx.x;
  if (m >= M_) return;
  float w0[NN_], w1[NN_];
  int col[NN_];
#pragma unroll
  for (int n = 0; n < NN_; n++) {
    int e = m * NN_ + n;
    float p0 = pseudo[e * 2], p1 = pseudo[e * 2 + 1];
    float emb[5];
#pragma unroll
    for (int d = 0; d < 5; d++)
      emb[d] = p0 * edge_w[d * 2] + p1 * edge_w[d * 2 + 1] + edge_b[d];
    float a0 = 0.f, a1 = 0.f;
#pragma unroll
    for (int j = 0; j < 4; j++) {
      float qa = 0.f, qb = 0.f;
#pragma unroll
      for (int d = 0; d < 5; d++) {
        float u0 = emb[d] - mu0[j * 5 + d];
        qa += u0 * u0 * sg0[j * 5 + d];
        float u1 = emb[d] - mu1[j * 5 + d];
        qb += u1 * u1 * sg1[j * 5 + d];
      }
      a0 += safeexp(-0.5f * qa);
      a1 += safeexp(-0.5f * qb);
    }
    w0[n] = a0; w1[n] = a1;
    col[n] = Lidx[e] % M_;
  }
  float mx0 = w0[0], mx1 = w1[0];
#pragma unroll
  for (int n = 1; n < NN_; n++) { mx0 = fmaxf(mx0, w0[n]); mx1 = fmaxf(mx1, w1[n]); }
  float s0 = 0.f, s1 = 0.f;
#pragma unroll
  for (int n = 0; n < NN_; n++) {
    w0[n] = safeexp(w0[n] - mx0); s0 += w0[n];
    w1[n] = safeexp(w1[n] - mx1); s1 += w1[n];
  }
  float r0 = 1.f / s0, r1 = 1.f / s1;
#pragma unroll
  for (int n = 0; n < NN_; n++) {
    bool last = true;                       // numpy fancy-set: last duplicate wins
#pragma unroll
    for (int n2 = n + 1; n2 < NN_; n2++)
      if (col[n2] == col[n]) last = false;
    int e = m * NN_ + n;
    we0[e] = last ? w0[n] * r0 : 0.f;
    we1[e] = last ? w1[n] * r1 : 0.f;
    colb[e] = col[n];
  }
}

// ---------------------------------------------------------------- proj0 (MFMA): G[r][0:32]=x@l1w0.T, G[r][32:64]=x@l2w0.T
__global__ __launch_bounds__(256) void proj0_kernel(
    const float* __restrict__ x, const float* __restrict__ l1w0,
    const float* __restrict__ l2w0, float* __restrict__ G) {
  int lane = threadIdx.x & 63, wave = threadIdx.x >> 6;
  int l16 = lane & 15, quad = lane >> 4;
  int tile = blockIdx.x * 4 + wave;            // 2048 tiles of 16 rows
  s16x8 bf[4][4];
#pragma unroll
  for (int kit = 0; kit < 4; kit++) {
#pragma unroll
    for (int ct = 0; ct < 4; ct++) {
      int out = ct * 16 + l16;                 // 0..63
      const float* src = (out < 32 ? l1w0 + out * 128 : l2w0 + (out - 32) * 128)
                         + kit * 32 + quad * 8;
      bf[kit][ct] = cvt8v(*(const float4*)src, *(const float4*)(src + 4));
    }
  }
  f32x4 acc[4];
#pragma unroll
  for (int ct = 0; ct < 4; ct++) acc[ct] = (f32x4){0.f, 0.f, 0.f, 0.f};
  int row = tile * 16 + l16;
  const float* xr = x + (size_t)row * 128 + quad * 8;
#pragma unroll
  for (int kit = 0; kit < 4; kit++) {
    const float* ap = xr + kit * 32;
    s16x8 a = cvt8v(*(const float4*)ap, *(const float4*)(ap + 4));
#pragma unroll
    for (int ct = 0; ct < 4; ct++)
      acc[ct] = __builtin_amdgcn_mfma_f32_16x16x32_bf16(a, bf[kit][ct], acc[ct], 0, 0, 0);
  }
  int rbase = tile * 16 + quad * 4;            // C/D: col=lane&15, row=quad*4+i (m89)
#pragma unroll
  for (int ct = 0; ct < 4; ct++)
#pragma unroll
    for (int i = 0; i < 4; i++)
      G[(size_t)(rbase + i) * 64 + ct * 16 + l16] = acc[ct][i];
}

// ---------------------------------------------------------------- conv0: h0 = L.G1 + G2 + b; BN0 partials
__global__ __launch_bounds__(256) void conv0_kernel(
    const float* __restrict__ G,
    const float* __restrict__ we0, const int* __restrict__ colb,
    const float* __restrict__ l1b0, const float* __restrict__ l2b0,
    float* __restrict__ h0, float* __restrict__ bns, float* __restrict__ bnq) {
  int t = blockIdx.x * 256 + threadIdx.x;
  int r = t >> 5, c = t & 31;
  int b = r >> 12, m = r & 4095;
  const float* Gb = G + ((size_t)b << 18);     // b*4096*64
  float acc = 0.f;
  int eb = m << 4;
#pragma unroll 4
  for (int nn = 0; nn < NN_; nn++) {
    float wv = we0[eb + nn];
    int cn = colb[eb + nn];
    acc += wv * Gb[cn * 64 + c];               // G1 part
  }
  float hv = acc + G[(size_t)r * 64 + 32 + c] + l1b0[c] + l2b0[c];
  h0[t] = hv;
  int slot = blockIdx.x & 255;
  atomicAdd(&bns[c * 256 + slot], hv);
  atomicAdd(&bnq[c * 256 + slot], hv * hv);
}

// ---------------------------------------------------------------- BN finalize (sum 256 slots)
__global__ void bnfin_kernel(const float* __restrict__ bns, const float* __restrict__ bnq,
                             const float* __restrict__ g, const float* __restrict__ bb,
                             float* __restrict__ scale, float* __restrict__ shift) {
  int c = threadIdx.x;
  if (c >= 32) return;
  float s = 0.f, q = 0.f;
  for (int i = 0; i < 256; i++) { s += bns[c * 256 + i]; q += bnq[c * 256 + i]; }
  float mean = s * (1.f / 32768.f);
  float var = fmaxf(q * (1.f / 32768.f) - mean * mean, 0.f);
  float sc = g[c] * rsqrtf(var + 1e-5f);
  scale[c] = sc;
  shift[c] = bb[c] - mean * sc;
}

// ---------------------------------------------------------------- proj1 (MFMA, K=32): a=relu(bn0(h0)); G=[a@l1w1.T | a@l2w1.T]
__global__ __launch_bounds__(256) void proj1_kernel(
    const float* __restrict__ h0, const float* __restrict__ sc0,
    const float* __restrict__ l1w1, const float* __restrict__ l2w1,
    float* __restrict__ G) {
  int lane = threadIdx.x & 63, wave = threadIdx.x >> 6;
  int l16 = lane & 15, quad = lane >> 4;
  int tile = blockIdx.x * 4 + wave;
  s16x8 bf[4];
#pragma unroll
  for (int ct = 0; ct < 4; ct++) {
    int out = ct * 16 + l16;
    const float* src = (out < 32 ? l1w1 + out * 32 : l2w1 + (out - 32) * 32) + quad * 8;
    bf[ct] = cvt8v(*(const float4*)src, *(const float4*)(src + 4));
  }
  // per-thread BN params for channels quad*8 .. quad*8+7
  float scv[8], shv[8];
#pragma unroll
  for (int j = 0; j < 8; j++) {
    scv[j] = sc0[quad * 8 + j];
    shv[j] = sc0[32 + quad * 8 + j];
  }
  int row = tile * 16 + l16;
  const float* hr = h0 + (size_t)row * 32 + quad * 8;
  float4 hv0 = *(const float4*)hr;
  float4 hv1 = *(const float4*)(hr + 4);
  float av[8] = {hv0.x, hv0.y, hv0.z, hv0.w, hv1.x, hv1.y, hv1.z, hv1.w};
  s16x8 a;
#pragma unroll
  for (int j = 0; j < 8; j++)
    a[j] = (short)f2bf(fmaxf(av[j] * scv[j] + shv[j], 0.f));
  f32x4 acc[4];
#pragma unroll
  for (int ct = 0; ct < 4; ct++) {
    f32x4 z = {0.f, 0.f, 0.f, 0.f};
    acc[ct] = __builtin_amdgcn_mfma_f32_16x16x32_bf16(a, bf[ct], z, 0, 0, 0);
  }
  int rbase = tile * 16 + quad * 4;
#pragma unroll
  for (int ct = 0; ct < 4; ct++)
#pragma unroll
    for (int i = 0; i < 4; i++)
      G[(size_t)(rbase + i) * 64 + ct * 16 + l16] = acc[ct][i];
}

// ---------------------------------------------------------------- conv1: h1 = L.G1 + G2 + b; BN1 partials
__global__ __launch_bounds__(256) void conv1_kernel(
    const float* __restrict__ G,
    const float* __restrict__ we1, const int* __restrict__ colb,
    const float* __restrict__ l1b1, const float* __restrict__ l2b1,
    float* __restrict__ h1, float* __restrict__ bns, float* __restrict__ bnq) {
  int t = blockIdx.x * 256 + threadIdx.x;
  int r = t >> 5, c = t & 31;
  int b = r >> 12, m = r & 4095;
  const float* Gb = G + ((size_t)b << 18);
  float acc = 0.f;
  int eb = m << 4;
#pragma unroll 4
  for (int nn = 0; nn < NN_; nn++) {
    float wv = we1[eb + nn];
    int cn = colb[eb + nn];
    acc += wv * Gb[cn * 64 + c];
  }
  float hv = acc + G[(size_t)r * 64 + 32 + c] + l1b1[c] + l2b1[c];
  h1[t] = hv;
  int slot = blockIdx.x & 255;
  atomicAdd(&bns[c * 256 + slot], hv);
  atomicAdd(&bnq[c * 256 + slot], hv * hv);
}

// ---------------------------------------------------------------- fc1: block=(kc,og); ALL 8 batches -> fc1w read ONCE
__global__ __launch_bounds__(256, 4) void fc1_kernel(
    const float* __restrict__ h1, const float* __restrict__ sc1,
    const float* __restrict__ fc1w, float* __restrict__ fc1acc) {
  __shared__ float a1s[8][1024];
  int kc = blockIdx.x >> 3;                 // 0..127
  int og = blockIdx.x & 7;                  // 0..7 -> outputs og*32..og*32+31
  int kbase = kc << 10;
  int obase = og << 5;
  for (int idx = threadIdx.x; idx < 8192; idx += 256) {
    int b = idx >> 10, k = idx & 1023;
    int c = k & 31;
    a1s[b][k] = fmaxf(h1[((size_t)b << 17) + kbase + k] * sc1[c] + sc1[32 + c], 0.f);
  }
  __syncthreads();
  int lane = threadIdx.x & 63, wave = threadIdx.x >> 6;
  float acc[8][8];                           // [out i][batch b]
#pragma unroll
  for (int i = 0; i < 8; i++)
#pragma unroll
    for (int b = 0; b < 8; b++) acc[i][b] = 0.f;
#pragma unroll
  for (int it = 0; it < 4; it++) {
    float4 h4[8];
#pragma unroll
    for (int b = 0; b < 8; b++) h4[b] = *(const float4*)&a1s[b][it * 256 + lane * 4];
#pragma unroll
    for (int i = 0; i < 8; i++) {
      int o = obase + wave * 8 + i;
      const float* wp = fc1w + (size_t)o * 131072 + kbase + it * 256 + lane * 4;
      float4 w4 = *(const float4*)wp;
#pragma unroll
      for (int b = 0; b < 8; b++)
        acc[i][b] += w4.x * h4[b].x + w4.y * h4[b].y + w4.z * h4[b].z + w4.w * h4[b].w;
    }
  }
  float myval = 0.f;
#pragma unroll
  for (int i = 0; i < 8; i++) {
#pragma unroll
    for (int b = 0; b < 8; b++) {
      float v = acc[i][b];
#pragma unroll
      for (int off = 1; off < 64; off <<= 1) v += __shfl_xor(v, off);
      if (lane == i * 8 + b) myval = v;
    }
  }
  atomicAdd(&fc1acc[(lane & 7) * 256 + obase + wave * 8 + (lane >> 3)], myval);
}

// ---------------------------------------------------------------- fc2 -> fp32 out
__global__ void fc2_kernel(const float* __restrict__ fc1acc,
                           const float* __restrict__ fc2w,
                           const float* __restrict__ fc2b,
                           float* __restrict__ out) {
  int t = blockIdx.x * blockDim.x + threadIdx.x;
  if (t >= 424) return;
  int b = t / 53, j = t - b * 53;
  float s = fc2b[j];
  const float* fa = fc1acc + b * 256;
  const float* wr = fc2w + j * 256;
#pragma unroll 8
  for (int o = 0; o < 256; o++) s += fmaxf(fa[o], 0.f) * wr[o];
  out[t] = s;
}

// ---------------------------------------------------------------- launch
extern "C" void kernel_launch(void* const* d_in, const int* in_sizes, int n_in,
                              void* d_out, int out_size, void* d_ws, size_t ws_size,
                              hipStream_t stream) {
  float* out = (float*)d_out;
  int bad = 0;
  if (n_in != 25) bad = 2;
  else if (in_sizes[0] != 4194304) bad = 3;
  else if (in_sizes[2] != 65536) bad = 4;
  else if (in_sizes[21] != 33554432) bad = 5;
  else if (out_size != 424) bad = 6;
  else if (ws_size < 13509120) bad = 1;
  if (bad) {
    poison_kernel<<<2, 256, 0, stream>>>(out, out_size, (float)bad * 1.0e6f);
    return;
  }

  const float* x      = (const float*)d_in[0];
  const float* pseudo = (const float*)d_in[1];
  const int*   Lidx   = (const int*)d_in[2];
  const float* edge_w = (const float*)d_in[3];
  const float* edge_b = (const float*)d_in[4];
  const float* mu0    = (const float*)d_in[5];
  const float* sg0    = (const float*)d_in[6];
  const float* mu1    = (const float*)d_in[7];
  const float* sg1    = (const float*)d_in[8];
  const float* l1w0   = (const float*)d_in[9];
  const float* l1b0   = (const float*)d_in[10];
  const float* l2w0   = (const float*)d_in[11];
  const float* l2b0   = (const float*)d_in[12];
  const float* l1w1   = (const float*)d_in[13];
  const float* l1b1   = (const float*)d_in[14];
  const float* l2w1   = (const float*)d_in[15];
  const float* l2b1   = (const float*)d_in[16];
  const float* bng0   = (const float*)d_in[17];
  const float* bnb0   = (const float*)d_in[18];
  const float* bng1   = (const float*)d_in[19];
  const float* bnb1   = (const float*)d_in[20];
  const float* fc1w   = (const float*)d_in[21];
  const float* fc1b   = (const float*)d_in[22];
  const float* fc2w   = (const float*)d_in[23];
  const float* fc2b   = (const float*)d_in[24];

  char* Wp = (char*)d_ws;
  int*   colb   = (int*)  (Wp + 0);          // 65536 i32
  float* we0    = (float*)(Wp + 262144);     // 65536 f32
  float* we1    = (float*)(Wp + 524288);     // 65536 f32
  float* G      = (float*)(Wp + 786432);     // 32768 x 64 f32 (8 MB): [.,0:32]=G1, [.,32:64]=G2
  float* h0     = (float*)(Wp + 9175040);    // 32768 x 32 f32 (4 MB)
  float* h1     = (float*)(Wp + 9175040);    // aliases h0 (h0 dead after proj1)
  float* bn     = (float*)(Wp + 13369344);   // 4 x (32ch x 256 slots) f32
  float* sc     = (float*)(Wp + 13500416);   // scale0,shift0,scale1,shift1
  float* fc1acc = (float*)(Wp + 13500928);   // 8x256 f32

  init_kernel<<<136, 256, 0, stream>>>(fc1acc, fc1b, bn);
  attn_kernel<<<16, 256, 0, stream>>>(pseudo, Lidx, edge_w, edge_b,
                                      mu0, sg0, mu1, sg1, we0, we1, colb);
  proj0_kernel<<<512, 256, 0, stream>>>(x, l1w0, l2w0, G);
  conv0_kernel<<<4096, 256, 0, stream>>>(G, we0, colb, l1b0, l2b0,
                                         h0, bn, bn + 8192);
  bnfin_kernel<<<1, 32, 0, stream>>>(bn, bn + 8192, bng0, bnb0, sc, sc + 32);
  proj1_kernel<<<512, 256, 0, stream>>>(h0, sc, l1w1, l2w1, G);
  conv1_kernel<<<4096, 256, 0, stream>>>(G, we1, colb, l1b1, l2b1,
                                         h1, bn + 16384, bn + 24576);
  bnfin_kernel<<<1, 32, 0, stream>>>(bn + 16384, bn + 24576, bng1, bnb1,
                                     sc + 64, sc + 96);
  fc1_kernel<<<1024, 256, 0, stream>>>(h1, sc + 64, fc1w, fc1acc);
  fc2_kernel<<<2, 256, 0, stream>>>(fc1acc, fc2w, fc2b, out);
}

// Round 8
// 389.404 us; speedup vs baseline: 2.4926x; 1.4642x over previous
//
#include <hip/hip_runtime.h>

#define B_ 8
#define M_ 4096
#define W_ 128
#define C_ 32
#define NN_ 16

typedef short s16x8 __attribute__((ext_vector_type(8)));
typedef float f32x4 __attribute__((ext_vector_type(4)));

static __device__ __forceinline__ unsigned short f2bf(float f) {
  unsigned u = __builtin_bit_cast(unsigned, f);
  u = u + 0x7FFFu + ((u >> 16) & 1u);   // RNE
  return (unsigned short)(u >> 16);
}
static __device__ __forceinline__ s16x8 cvt8v(float4 a, float4 b) {
  s16x8 r;
  r[0] = (short)f2bf(a.x); r[1] = (short)f2bf(a.y);
  r[2] = (short)f2bf(a.z); r[3] = (short)f2bf(a.w);
  r[4] = (short)f2bf(b.x); r[5] = (short)f2bf(b.y);
  r[6] = (short)f2bf(b.z); r[7] = (short)f2bf(b.w);
  return r;
}
static __device__ __forceinline__ float safeexp(float a) {
  return expf(fminf(a, 87.f));
}

// ---------------------------------------------------------------- poison (diagnostic sentinel)
__global__ void poison_kernel(float* __restrict__ out, int n, float val) {
  int t = blockIdx.x * blockDim.x + threadIdx.x;
  if (t < n) out[t] = val;
}

// ---------------------------------------------------------------- init: fc1acc = fc1b; bn slots = 0
__global__ __launch_bounds__(256) void init_kernel(
    float* __restrict__ fc1acc, const float* __restrict__ fc1b,
    float* __restrict__ bn) {
  int g = blockIdx.x * 256 + threadIdx.x;
  if (g < 2048) fc1acc[g] = fc1b[g & 255];
  else if (g < 34816) bn[g - 2048] = 0.f;
}

// ---------------------------------------------------------------- attention: one THREAD per row (proven)
__global__ __launch_bounds__(256) void attn_kernel(
    const float* __restrict__ pseudo, const int* __restrict__ Lidx,
    const float* __restrict__ edge_w, const float* __restrict__ edge_b,
    const float* __restrict__ mu0, const float* __restrict__ sg0,
    const float* __restrict__ mu1, const float* __restrict__ sg1,
    float* __restrict__ we0, float* __restrict__ we1, int* __restrict__ colb) {
  int m = blockIdx.x * 256 + threadIdx.x;
  if (m >= M_) return;
  float w0[NN_], w1[NN_];
  int col[NN_];
#pragma unroll
  for (int n = 0; n < NN_; n++) {
    int e = m * NN_ + n;
    float p0 = pseudo[e * 2], p1 = pseudo[e * 2 + 1];
    float emb[5];
#pragma unroll
    for (int d = 0; d < 5; d++)
      emb[d] = p0 * edge_w[d * 2] + p1 * edge_w[d * 2 + 1] + edge_b[d];
    float a0 = 0.f, a1 = 0.f;
#pragma unroll
    for (int j = 0; j < 4; j++) {
      float qa = 0.f, qb = 0.f;
#pragma unroll
      for (int d = 0; d < 5; d++) {
        float u0 = emb[d] - mu0[j * 5 + d];
        qa += u0 * u0 * sg0[j * 5 + d];
        float u1 = emb[d] - mu1[j * 5 + d];
        qb += u1 * u1 * sg1[j * 5 + d];
      }
      a0 += safeexp(-0.5f * qa);
      a1 += safeexp(-0.5f * qb);
    }
    w0[n] = a0; w1[n] = a1;
    col[n] = Lidx[e] % M_;
  }
  float mx0 = w0[0], mx1 = w1[0];
#pragma unroll
  for (int n = 1; n < NN_; n++) { mx0 = fmaxf(mx0, w0[n]); mx1 = fmaxf(mx1, w1[n]); }
  float s0 = 0.f, s1 = 0.f;
#pragma unroll
  for (int n = 0; n < NN_; n++) {
    w0[n] = safeexp(w0[n] - mx0); s0 += w0[n];
    w1[n] = safeexp(w1[n] - mx1); s1 += w1[n];
  }
  float r0 = 1.f / s0, r1 = 1.f / s1;
#pragma unroll
  for (int n = 0; n < NN_; n++) {
    bool last = true;                       // numpy fancy-set: last duplicate wins
#pragma unroll
    for (int n2 = n + 1; n2 < NN_; n2++)
      if (col[n2] == col[n]) last = false;
    int e = m * NN_ + n;
    we0[e] = last ? w0[n] * r0 : 0.f;
    we1[e] = last ? w1[n] * r1 : 0.f;
    colb[e] = col[n];
  }
}

// ---------------------------------------------------------------- proj0 (MFMA): G[r][0:32]=x@l1w0.T, G[r][32:64]=x@l2w0.T
__global__ __launch_bounds__(256) void proj0_kernel(
    const float* __restrict__ x, const float* __restrict__ l1w0,
    const float* __restrict__ l2w0, float* __restrict__ G) {
  int lane = threadIdx.x & 63, wave = threadIdx.x >> 6;
  int l16 = lane & 15, quad = lane >> 4;
  int tile = blockIdx.x * 4 + wave;            // 2048 tiles of 16 rows
  s16x8 bf[4][4];
#pragma unroll
  for (int kit = 0; kit < 4; kit++) {
#pragma unroll
    for (int ct = 0; ct < 4; ct++) {
      int out = ct * 16 + l16;                 // 0..63
      const float* src = (out < 32 ? l1w0 + out * 128 : l2w0 + (out - 32) * 128)
                         + kit * 32 + quad * 8;
      bf[kit][ct] = cvt8v(*(const float4*)src, *(const float4*)(src + 4));
    }
  }
  f32x4 acc[4];
#pragma unroll
  for (int ct = 0; ct < 4; ct++) acc[ct] = (f32x4){0.f, 0.f, 0.f, 0.f};
  int row = tile * 16 + l16;
  const float* xr = x + (size_t)row * 128 + quad * 8;
#pragma unroll
  for (int kit = 0; kit < 4; kit++) {
    const float* ap = xr + kit * 32;
    s16x8 a = cvt8v(*(const float4*)ap, *(const float4*)(ap + 4));
#pragma unroll
    for (int ct = 0; ct < 4; ct++)
      acc[ct] = __builtin_amdgcn_mfma_f32_16x16x32_bf16(a, bf[kit][ct], acc[ct], 0, 0, 0);
  }
  int rbase = tile * 16 + quad * 4;            // C/D: col=lane&15, row=quad*4+i (m89)
#pragma unroll
  for (int ct = 0; ct < 4; ct++)
#pragma unroll
    for (int i = 0; i < 4; i++)
      G[(size_t)(rbase + i) * 64 + ct * 16 + l16] = acc[ct][i];
}

// ---------------------------------------------------------------- conv (shared for both layers):
// h = L.G1 + G2 + b1 + b2; BN partials via LDS reduction.
// Block = 8 rows x 32 ch. Stage (we,col) in LDS -> 16 independent gathers in flight.
__global__ __launch_bounds__(256) void conv_kernel(
    const float* __restrict__ G,
    const float* __restrict__ we, const int* __restrict__ colb,
    const float* __restrict__ b1c, const float* __restrict__ b2c,
    float* __restrict__ h, float* __restrict__ bns, float* __restrict__ bnq) {
  __shared__ float s_we[8][16];
  __shared__ int   s_cn[8][16];
  __shared__ float s_s[32], s_q[32];
  int tid = threadIdx.x;
  if (tid < 128) {
    int row = tid >> 4, nn = tid & 15;
    int m = (blockIdx.x * 8 + row) & 4095;     // attn arrays are per-m (batch-independent)
    s_we[row][nn] = we[m * 16 + nn];
    s_cn[row][nn] = colb[m * 16 + nn];
  } else if (tid < 160) {
    s_s[tid - 128] = 0.f;
    s_q[tid - 128] = 0.f;
  }
  __syncthreads();
  int row = tid >> 5, c = tid & 31;
  int r = blockIdx.x * 8 + row;
  int b = r >> 12;
  const float* Gb = G + ((size_t)b << 18);     // b*4096*64
  float acc = 0.f;
#pragma unroll
  for (int nn = 0; nn < NN_; nn++)             // all 16 loads independent -> in flight together
    acc += s_we[row][nn] * Gb[s_cn[row][nn] * 64 + c];
  float hv = acc + G[(size_t)r * 64 + 32 + c] + b1c[c] + b2c[c];
  h[(size_t)r * 32 + c] = hv;
  atomicAdd(&s_s[c], hv);                      // LDS atomic (ds_add_f32), 8-way per addr
  atomicAdd(&s_q[c], hv * hv);
  __syncthreads();
  if (tid < 32) {
    int slot = blockIdx.x & 255;
    atomicAdd(&bns[tid * 256 + slot], s_s[tid]);
    atomicAdd(&bnq[tid * 256 + slot], s_q[tid]);
  }
}

// ---------------------------------------------------------------- BN finalize (sum 256 slots)
__global__ void bnfin_kernel(const float* __restrict__ bns, const float* __restrict__ bnq,
                             const float* __restrict__ g, const float* __restrict__ bb,
                             float* __restrict__ scale, float* __restrict__ shift) {
  int c = threadIdx.x;
  if (c >= 32) return;
  float s = 0.f, q = 0.f;
  for (int i = 0; i < 256; i++) { s += bns[c * 256 + i]; q += bnq[c * 256 + i]; }
  float mean = s * (1.f / 32768.f);
  float var = fmaxf(q * (1.f / 32768.f) - mean * mean, 0.f);
  float sc = g[c] * rsqrtf(var + 1e-5f);
  scale[c] = sc;
  shift[c] = bb[c] - mean * sc;
}

// ---------------------------------------------------------------- proj1 (MFMA, K=32): a=relu(bn0(h0)); G=[a@l1w1.T | a@l2w1.T]
__global__ __launch_bounds__(256) void proj1_kernel(
    const float* __restrict__ h0, const float* __restrict__ sc0,
    const float* __restrict__ l1w1, const float* __restrict__ l2w1,
    float* __restrict__ G) {
  int lane = threadIdx.x & 63, wave = threadIdx.x >> 6;
  int l16 = lane & 15, quad = lane >> 4;
  int tile = blockIdx.x * 4 + wave;
  s16x8 bf[4];
#pragma unroll
  for (int ct = 0; ct < 4; ct++) {
    int out = ct * 16 + l16;
    const float* src = (out < 32 ? l1w1 + out * 32 : l2w1 + (out - 32) * 32) + quad * 8;
    bf[ct] = cvt8v(*(const float4*)src, *(const float4*)(src + 4));
  }
  float scv[8], shv[8];
#pragma unroll
  for (int j = 0; j < 8; j++) {
    scv[j] = sc0[quad * 8 + j];
    shv[j] = sc0[32 + quad * 8 + j];
  }
  int row = tile * 16 + l16;
  const float* hr = h0 + (size_t)row * 32 + quad * 8;
  float4 hv0 = *(const float4*)hr;
  float4 hv1 = *(const float4*)(hr + 4);
  float av[8] = {hv0.x, hv0.y, hv0.z, hv0.w, hv1.x, hv1.y, hv1.z, hv1.w};
  s16x8 a;
#pragma unroll
  for (int j = 0; j < 8; j++)
    a[j] = (short)f2bf(fmaxf(av[j] * scv[j] + shv[j], 0.f));
  f32x4 acc[4];
#pragma unroll
  for (int ct = 0; ct < 4; ct++) {
    f32x4 z = {0.f, 0.f, 0.f, 0.f};
    acc[ct] = __builtin_amdgcn_mfma_f32_16x16x32_bf16(a, bf[ct], z, 0, 0, 0);
  }
  int rbase = tile * 16 + quad * 4;
#pragma unroll
  for (int ct = 0; ct < 4; ct++)
#pragma unroll
    for (int i = 0; i < 4; i++)
      G[(size_t)(rbase + i) * 64 + ct * 16 + l16] = acc[ct][i];
}

// ---------------------------------------------------------------- fc1: block=(kc,og); ALL 8 batches -> fc1w read ONCE
__global__ __launch_bounds__(256, 4) void fc1_kernel(
    const float* __restrict__ h1, const float* __restrict__ sc1,
    const float* __restrict__ fc1w, float* __restrict__ fc1acc) {
  __shared__ float a1s[8][1024];
  int kc = blockIdx.x >> 3;                 // 0..127
  int og = blockIdx.x & 7;                  // outputs og*32..og*32+31
  int kbase = kc << 10;
  int obase = og << 5;
  for (int idx = threadIdx.x; idx < 8192; idx += 256) {
    int b = idx >> 10, k = idx & 1023;
    int c = k & 31;
    a1s[b][k] = fmaxf(h1[((size_t)b << 17) + kbase + k] * sc1[c] + sc1[32 + c], 0.f);
  }
  __syncthreads();
  int lane = threadIdx.x & 63, wave = threadIdx.x >> 6;
  float acc[8][8];                           // [out i][batch b]
#pragma unroll
  for (int i = 0; i < 8; i++)
#pragma unroll
    for (int b = 0; b < 8; b++) acc[i][b] = 0.f;
#pragma unroll
  for (int it = 0; it < 4; it++) {
    float4 h4[8];
#pragma unroll
    for (int b = 0; b < 8; b++) h4[b] = *(const float4*)&a1s[b][it * 256 + lane * 4];
#pragma unroll
    for (int i = 0; i < 8; i++) {
      int o = obase + wave * 8 + i;
      const float* wp = fc1w + (size_t)o * 131072 + kbase + it * 256 + lane * 4;
      float4 w4 = *(const float4*)wp;
#pragma unroll
      for (int b = 0; b < 8; b++)
        acc[i][b] += w4.x * h4[b].x + w4.y * h4[b].y + w4.z * h4[b].z + w4.w * h4[b].w;
    }
  }
  float myval = 0.f;
#pragma unroll
  for (int i = 0; i < 8; i++) {
#pragma unroll
    for (int b = 0; b < 8; b++) {
      float v = acc[i][b];
#pragma unroll
      for (int off = 1; off < 64; off <<= 1) v += __shfl_xor(v, off);
      if (lane == i * 8 + b) myval = v;
    }
  }
  atomicAdd(&fc1acc[(lane & 7) * 256 + obase + wave * 8 + (lane >> 3)], myval);
}

// ---------------------------------------------------------------- fc2 -> fp32 out
__global__ void fc2_kernel(const float* __restrict__ fc1acc,
                           const float* __restrict__ fc2w,
                           const float* __restrict__ fc2b,
                           float* __restrict__ out) {
  int t = blockIdx.x * blockDim.x + threadIdx.x;
  if (t >= 424) return;
  int b = t / 53, j = t - b * 53;
  float s = fc2b[j];
  const float* fa = fc1acc + b * 256;
  const float* wr = fc2w + j * 256;
#pragma unroll 8
  for (int o = 0; o < 256; o++) s += fmaxf(fa[o], 0.f) * wr[o];
  out[t] = s;
}

// ---------------------------------------------------------------- launch
extern "C" void kernel_launch(void* const* d_in, const int* in_sizes, int n_in,
                              void* d_out, int out_size, void* d_ws, size_t ws_size,
                              hipStream_t stream) {
  float* out = (float*)d_out;
  int bad = 0;
  if (n_in != 25) bad = 2;
  else if (in_sizes[0] != 4194304) bad = 3;
  else if (in_sizes[2] != 65536) bad = 4;
  else if (in_sizes[21] != 33554432) bad = 5;
  else if (out_size != 424) bad = 6;
  else if (ws_size < 13509120) bad = 1;
  if (bad) {
    poison_kernel<<<2, 256, 0, stream>>>(out, out_size, (float)bad * 1.0e6f);
    return;
  }

  const float* x      = (const float*)d_in[0];
  const float* pseudo = (const float*)d_in[1];
  const int*   Lidx   = (const int*)d_in[2];
  const float* edge_w = (const float*)d_in[3];
  const float* edge_b = (const float*)d_in[4];
  const float* mu0    = (const float*)d_in[5];
  const float* sg0    = (const float*)d_in[6];
  const float* mu1    = (const float*)d_in[7];
  const float* sg1    = (const float*)d_in[8];
  const float* l1w0   = (const float*)d_in[9];
  const float* l1b0   = (const float*)d_in[10];
  const float* l2w0   = (const float*)d_in[11];
  const float* l2b0   = (const float*)d_in[12];
  const float* l1w1   = (const float*)d_in[13];
  const float* l1b1   = (const float*)d_in[14];
  const float* l2w1   = (const float*)d_in[15];
  const float* l2b1   = (const float*)d_in[16];
  const float* bng0   = (const float*)d_in[17];
  const float* bnb0   = (const float*)d_in[18];
  const float* bng1   = (const float*)d_in[19];
  const float* bnb1   = (const float*)d_in[20];
  const float* fc1w   = (const float*)d_in[21];
  const float* fc1b   = (const float*)d_in[22];
  const float* fc2w   = (const float*)d_in[23];
  const float* fc2b   = (const float*)d_in[24];

  char* Wp = (char*)d_ws;
  int*   colb   = (int*)  (Wp + 0);          // 65536 i32
  float* we0    = (float*)(Wp + 262144);     // 65536 f32
  float* we1    = (float*)(Wp + 524288);     // 65536 f32
  float* G      = (float*)(Wp + 786432);     // 32768 x 64 f32 (8 MB): [.,0:32]=G1, [.,32:64]=G2
  float* h0     = (float*)(Wp + 9175040);    // 32768 x 32 f32 (4 MB)
  float* h1     = (float*)(Wp + 9175040);    // aliases h0 (h0 dead after proj1)
  float* bn     = (float*)(Wp + 13369344);   // 4 x (32ch x 256 slots) f32
  float* sc     = (float*)(Wp + 13500416);   // scale0,shift0,scale1,shift1
  float* fc1acc = (float*)(Wp + 13500928);   // 8x256 f32

  init_kernel<<<136, 256, 0, stream>>>(fc1acc, fc1b, bn);
  attn_kernel<<<16, 256, 0, stream>>>(pseudo, Lidx, edge_w, edge_b,
                                      mu0, sg0, mu1, sg1, we0, we1, colb);
  proj0_kernel<<<512, 256, 0, stream>>>(x, l1w0, l2w0, G);
  conv_kernel<<<4096, 256, 0, stream>>>(G, we0, colb, l1b0, l2b0,
                                        h0, bn, bn + 8192);
  bnfin_kernel<<<1, 32, 0, stream>>>(bn, bn + 8192, bng0, bnb0, sc, sc + 32);
  proj1_kernel<<<512, 256, 0, stream>>>(h0, sc, l1w1, l2w1, G);
  conv_kernel<<<4096, 256, 0, stream>>>(G, we1, colb, l1b1, l2b1,
                                        h1, bn + 16384, bn + 24576);
  bnfin_kernel<<<1, 32, 0, stream>>>(bn + 16384, bn + 24576, bng1, bnb1,
                                     sc + 64, sc + 96);
  fc1_kernel<<<1024, 256, 0, stream>>>(h1, sc + 64, fc1w, fc1acc);
  fc2_kernel<<<2, 256, 0, stream>>>(fc1acc, fc2w, fc2b, out);
}